// Round 4
// baseline (497.946 us; speedup 1.0000x reference)
//
#include <hip/hip_runtime.h>

// Problem constants (from reference)
#define N_TOT   262144
#define KCODES  1024
#define DIM     256
#define DECAY   0.99f
#define OMDECAY 0.01f      // (1.0f - 0.99f) == 0.01f in f32
#define EPS     1e-5f

// ---------------------------------------------------------------------------
// Pass 1: histogram of indices -> counts[K]. int4 loads, device atomics.
// ---------------------------------------------------------------------------
__global__ void k_hist(const int4* __restrict__ idx4, int* __restrict__ counts) {
    int i = blockIdx.x * blockDim.x + threadIdx.x;   // 65536 threads, 1 int4 each
    int4 v = idx4[i];
    atomicAdd(&counts[v.x], 1);
    atomicAdd(&counts[v.y], 1);
    atomicAdd(&counts[v.z], 1);
    atomicAdd(&counts[v.w], 1);
}

// ---------------------------------------------------------------------------
// Pass 2: single block of K=1024 threads, shfl-based scan (2 barriers).
//   exclusive prefix sum -> offsets/cursor; new_cs -> d_out[0:K];
//   n = sum(new_cs); smoothed[k] = (new_cs+EPS)/(n+K*EPS)*n
// ---------------------------------------------------------------------------
__global__ void k_scan(const int* __restrict__ counts,
                       const float* __restrict__ cluster_size,
                       int* __restrict__ offsets,
                       int* __restrict__ cursor,
                       float* __restrict__ smoothed,
                       float* __restrict__ out_cs) {
    __shared__ int   wsum[16];
    __shared__ float wf[16];
    __shared__ float n_sh;
    const int t   = threadIdx.x;
    const int wid = t >> 6;
    const int l   = t & 63;

    const int c = counts[t];
    // wave-inclusive scan of c
    int v = c;
    #pragma unroll
    for (int d = 1; d < 64; d <<= 1) {
        int u = __shfl_up(v, d, 64);
        if (l >= d) v += u;
    }
    if (l == 63) wsum[wid] = v;

    const float ncs = cluster_size[t] * DECAY + OMDECAY * (float)c;
    out_cs[t] = ncs;
    // wave reduce of ncs
    float fs = ncs;
    #pragma unroll
    for (int d = 32; d; d >>= 1) fs += __shfl_xor(fs, d, 64);
    if (l == 0) wf[wid] = fs;
    __syncthreads();

    if (wid == 0) {
        // scan the 16 wave sums (lanes 0..15 hold them)
        int s = (l < 16) ? wsum[l] : 0;
        #pragma unroll
        for (int d = 1; d < 16; d <<= 1) {
            int u = __shfl_up(s, d, 64);
            if (l >= d) s += u;
        }
        if (l < 16) wsum[l] = s;          // inclusive scanned wave sums
        // reduce the 16 wave float sums
        float x = (l < 16) ? wf[l] : 0.f;
        #pragma unroll
        for (int d = 8; d; d >>= 1) x += __shfl_xor(x, d, 16);
        if (l == 0) n_sh = x;
    }
    __syncthreads();

    const int wbase = wid ? wsum[wid - 1] : 0;
    const int excl  = v + wbase - c;
    offsets[t] = excl;
    cursor[t]  = excl;

    const float n = n_sh;
    smoothed[t] = (ncs + EPS) / (n + (float)KCODES * EPS) * n;
}

// ---------------------------------------------------------------------------
// Pass 3: bucket row ids into segment-sorted order (counting sort, ids only)
// ---------------------------------------------------------------------------
__global__ void k_scatter(const int4* __restrict__ idx4,
                          int* __restrict__ cursor,
                          int* __restrict__ sorted) {
    int i = blockIdx.x * blockDim.x + threadIdx.x;   // 65536 threads, 1 int4 each
    int4 v = idx4[i];
    int b = i * 4;
    sorted[atomicAdd(&cursor[v.x], 1)] = b;
    sorted[atomicAdd(&cursor[v.y], 1)] = b + 1;
    sorted[atomicAdd(&cursor[v.z], 1)] = b + 2;
    sorted[atomicAdd(&cursor[v.w], 1)] = b + 3;
}

// ---------------------------------------------------------------------------
// Pass 4: one block per code k. Wave-per-row float4 gather:
//   wave w (of 4) handles rows j = w, w+4, ...; lane l holds columns 4l..4l+3.
//   Each row is ONE global_load_dwordx4 per wave (64 lanes x 16B = 1KB row).
//   Unroll 8 -> 8KB outstanding per wave. Cross-wave LDS reduce, fused
//   EMA + normalize epilogue with float4 stores.
// ---------------------------------------------------------------------------
__global__ void __launch_bounds__(256)
k_sum(const float4* __restrict__ enc4,      // [N*64] float4
      const float4* __restrict__ ea4,       // [K*64] float4
      const int* __restrict__ counts,
      const int* __restrict__ offsets,
      const int* __restrict__ sorted,
      const float* __restrict__ smoothed,
      float4* __restrict__ out4) {          // K/4 ++ K*64 ++ K*64 float4s
    const int k = blockIdx.x;
    const int t = threadIdx.x;
    const int w = t >> 6;     // wave 0..3
    const int l = t & 63;     // lane: columns 4l..4l+3
    const int start = offsets[k];
    const int cnt   = counts[k];

    float4 acc = make_float4(0.f, 0.f, 0.f, 0.f);
    int j = w;
    for (; j + 28 < cnt; j += 32) {          // rows j, j+4, ..., j+28 valid
        int r0 = sorted[start + j];
        int r1 = sorted[start + j + 4];
        int r2 = sorted[start + j + 8];
        int r3 = sorted[start + j + 12];
        int r4 = sorted[start + j + 16];
        int r5 = sorted[start + j + 20];
        int r6 = sorted[start + j + 24];
        int r7 = sorted[start + j + 28];
        float4 a0 = enc4[(size_t)r0 * 64 + l];
        float4 a1 = enc4[(size_t)r1 * 64 + l];
        float4 a2 = enc4[(size_t)r2 * 64 + l];
        float4 a3 = enc4[(size_t)r3 * 64 + l];
        float4 a4 = enc4[(size_t)r4 * 64 + l];
        float4 a5 = enc4[(size_t)r5 * 64 + l];
        float4 a6 = enc4[(size_t)r6 * 64 + l];
        float4 a7 = enc4[(size_t)r7 * 64 + l];
        acc.x += a0.x + a1.x + a2.x + a3.x + a4.x + a5.x + a6.x + a7.x;
        acc.y += a0.y + a1.y + a2.y + a3.y + a4.y + a5.y + a6.y + a7.y;
        acc.z += a0.z + a1.z + a2.z + a3.z + a4.z + a5.z + a6.z + a7.z;
        acc.w += a0.w + a1.w + a2.w + a3.w + a4.w + a5.w + a6.w + a7.w;
    }
    for (; j < cnt; j += 4) {
        int r = sorted[start + j];
        float4 a = enc4[(size_t)r * 64 + l];
        acc.x += a.x; acc.y += a.y; acc.z += a.z; acc.w += a.w;
    }

    __shared__ float4 red[3][64];
    if (w > 0) red[w - 1][l] = acc;
    __syncthreads();
    if (w == 0) {
        float4 p0 = red[0][l], p1 = red[1][l], p2 = red[2][l];
        acc.x += p0.x + p1.x + p2.x;
        acc.y += p0.y + p1.y + p2.y;
        acc.z += p0.z + p1.z + p2.z;
        acc.w += p0.w + p1.w + p2.w;

        float4 ea = ea4[(size_t)k * 64 + l];
        float4 nea;
        nea.x = ea.x * DECAY + OMDECAY * acc.x;
        nea.y = ea.y * DECAY + OMDECAY * acc.y;
        nea.z = ea.z * DECAY + OMDECAY * acc.z;
        nea.w = ea.w * DECAY + OMDECAY * acc.w;
        out4[KCODES / 4 + (size_t)k * 64 + l] = nea;

        const float s = smoothed[k];
        float4 nrm;
        nrm.x = nea.x / s; nrm.y = nea.y / s; nrm.z = nea.z / s; nrm.w = nea.w / s;
        out4[KCODES / 4 + (size_t)KCODES * 64 + (size_t)k * 64 + l] = nrm;
    }
}

// ---------------------------------------------------------------------------
extern "C" void kernel_launch(void* const* d_in, const int* in_sizes, int n_in,
                              void* d_out, int out_size, void* d_ws, size_t ws_size,
                              hipStream_t stream) {
    const int*   idx = (const int*)  d_in[0];   // indices      [N]
    const float* enc = (const float*)d_in[1];   // encodings    [N,D]
    const float* cs  = (const float*)d_in[2];   // cluster_size [K]
    const float* ea  = (const float*)d_in[3];   // embed_avg    [K,D]
    float* out = (float*)d_out;                 // [K] ++ [K,D] ++ [K,D]

    char* ws = (char*)d_ws;
    int*   counts   = (int*)  (ws);
    int*   offsets  = (int*)  (ws + 1 * KCODES * 4);
    int*   cursor   = (int*)  (ws + 2 * KCODES * 4);
    float* smoothed = (float*)(ws + 3 * KCODES * 4);
    int*   sorted   = (int*)  (ws + 4 * KCODES * 4);   // N ints

    hipMemsetAsync(counts, 0, KCODES * sizeof(int), stream);
    k_hist   <<<N_TOT / 4 / 256, 256, 0, stream>>>((const int4*)idx, counts);
    k_scan   <<<1, KCODES, 0, stream>>>(counts, cs, offsets, cursor, smoothed, out);
    k_scatter<<<N_TOT / 4 / 256, 256, 0, stream>>>((const int4*)idx, cursor, sorted);
    k_sum    <<<KCODES, 256, 0, stream>>>((const float4*)enc, (const float4*)ea,
                                          counts, offsets, sorted, smoothed,
                                          (float4*)out);
}